// Round 9
// baseline (143.365 us; speedup 1.0000x reference)
//
#include <hip/hip_runtime.h>

// SLAYER SNN forward, MI355X. Round 9.
// vs R8: (1) kf barriers are lgkm-only (asm s_waitcnt lgkmcnt(0) + s_barrier)
//        so the 8-deep u1 prefetch stays in flight across rounds instead of
//        being drained by __syncthreads' vmcnt(0); (2) kf barrier count 4->3
//        (after-dense barrier proven redundant); (3) k1's single-wave
//        __syncthreads replaced by a completed-lgkm wait (no barrier).
// All arithmetic / summation trees bit-identical to round 8 (absmax 0.0).

#define DECAY 0.9048374180359595f   // exp(-1/10)

// lgkm-only workgroup barrier: LDS writes completed + rendezvous, but global
// loads in flight are NOT drained (unlike __syncthreads on CDNA).
#define BAR_LGKM() asm volatile("s_waitcnt lgkmcnt(0)\n\ts_barrier" ::: "memory")
// single-wave LDS fence: all prior ds ops completed before any later ds issues.
#define FENCE_LGKM() asm volatile("s_waitcnt lgkmcnt(0)" ::: "memory")

// ---------------- k0: fold weights ----------------
// wl1[(cin*8 + e)*32 + c*8 + f], e,f in 0..7  (512 floats)
// wl2[c2*68 + cin*16 + e*4 + f]               (544 floats incl. unused pads)
__global__ __launch_bounds__(128) void k0_fold(const float* __restrict__ w1,
        const float* __restrict__ w2, const float* __restrict__ wp1,
        const float* __restrict__ wp2, float* __restrict__ wl1,
        float* __restrict__ wl2) {
    const int tid = threadIdx.x;
    const float p1 = wp1[0], p2 = wp2[0];
    for (int idx = tid; idx < 512; idx += 128) {
        const int f = idx & 7, c = (idx >> 3) & 3, e = (idx >> 5) & 7, cin = idx >> 8;
        const int cc = c * 2 + cin;
        int alo = e - 3; if (alo < 0) alo = 0;
        int ahi = e;     if (ahi > 4) ahi = 4;
        int blo = f - 3; if (blo < 0) blo = 0;
        int bhi = f;     if (bhi > 4) bhi = 4;
        float s = 0.f;
        for (int a = alo; a <= ahi; ++a)
            for (int b = blo; b <= bhi; ++b)
                s += w1[cc * 25 + a * 5 + b];
        wl1[(cin * 8 + e) * 32 + c * 8 + f] = s * p1;
    }
    for (int idx = tid; idx < 512; idx += 128) {
        const int c2 = idx & 7, f = (idx >> 3) & 3, e = (idx >> 5) & 3, cin = idx >> 7;
        int alo = e - 1; if (alo < 0) alo = 0;
        int ahi = e;     if (ahi > 2) ahi = 2;
        int blo = f - 1; if (blo < 0) blo = 0;
        int bhi = f;     if (bhi > 2) bhi = 2;
        float s = 0.f;
        for (int aa = alo; aa <= ahi; ++aa)
            for (int bb = blo; bb <= bhi; ++bb)
                s += w2[((c2 * 4 + cin) * 3 + aa) * 3 + bb];
        wl2[c2 * 68 + cin * 16 + e * 4 + f] = s * p2;
    }
}

// ---------------- k1: conv1+pool1, 8x8-tap stride-4 ----------------
// 6400 one-wave blocks; e-split lane pairs (R7). Barrier replaced by
// FENCE_LGKM (same-wave producer/consumer; completed-wait is sufficient).
__global__ __launch_bounds__(64) void k1(const float* __restrict__ x,
        const float* __restrict__ wg, float* __restrict__ u1) {
    __shared__ __align__(16) float xs[2 * 1296];   // 10.1 KB
    __shared__ __align__(16) float wl[512];        // 2 KB
    const int lane = threadIdx.x;
    const int frame = blockIdx.x;                  // = n*100 + t (x is n-major)
    const int n = frame / 100, t = frame % 100;

    *(float4*)(wl + 4 * lane)       = *(const float4*)(wg + 4 * lane);
    *(float4*)(wl + 256 + 4 * lane) = *(const float4*)(wg + 256 + 4 * lane);

    #pragma unroll
    for (int m0 = 0; m0 < 128; m0 += 64) {
        const int m = m0 + lane;
        if (m < 72) {
            const int cin = m / 36, rem = m % 36;
            const int rr = rem / 9, q4 = rem % 9;
            const int pr = (rr == 0) ? 0 : (rr == 1) ? 9 : (rr == 2) ? 26 : 35;
            *(float4*)(xs + cin * 1296 + pr * 36 + q4 * 4) = make_float4(0.f, 0.f, 0.f, 0.f);
        }
    }
    #pragma unroll
    for (int m0 = 0; m0 < 192; m0 += 64) {
        const int m = m0 + lane;
        if (m < 144) {
            const int cin = m / 72, rem = m % 72;
            const int side = rem & 1, pr = rem >> 1;
            *(float2*)(xs + cin * 1296 + pr * 36 + side * 34) = make_float2(0.f, 0.f);
        }
    }
    const float4* xg = (const float4*)(x + (size_t)frame * 2048);
    #pragma unroll
    for (int q = 0; q < 8; ++q) {
        const int m = q * 64 + lane;
        const float4 v = xg[m];
        const int li = 4 * m;
        const int cin = li >> 10, row = (li >> 5) & 31, col = li & 31;
        const int r = row + 2;
        const int pr = (r & 3) * 9 + (r >> 2);
        float* d = xs + cin * 1296 + pr * 36 + col + 2;
        *(float2*)(d)     = make_float2(v.x, v.y);
        *(float2*)(d + 2) = make_float2(v.z, v.w);
    }
    FENCE_LGKM();   // 1-wave block: ds writes completed; no s_barrier needed

    const int cp = lane >> 5;
    const int i  = (lane >> 2) & 7;
    const int jh = (lane >> 1) & 1;
    const int eh = lane & 1;

    float acc[2][4] = {{0.f, 0.f, 0.f, 0.f}, {0.f, 0.f, 0.f, 0.f}};
    const float* tb = xs + (i + eh) * 36 + jh * 16;
    #pragma unroll
    for (int cin = 0; cin < 2; ++cin) {
        #pragma unroll
        for (int et = 0; et < 4; ++et) {
            const int ro = cin * 1296 + et * 9 * 36;
            float xr[20];
            #pragma unroll
            for (int b = 0; b < 5; ++b)
                *(float4*)(xr + 4 * b) = *(const float4*)(tb + ro + 4 * b);
            float wv[16];
            const float* wp = wl + (cin * 8 + eh * 4 + et) * 32 + cp * 16;
            #pragma unroll
            for (int q = 0; q < 4; ++q)
                *(float4*)(wv + 4 * q) = *(const float4*)(wp + 4 * q);
            #pragma unroll
            for (int cl = 0; cl < 2; ++cl) {
                #pragma unroll
                for (int jj = 0; jj < 4; ++jj) {
                    const int o = 4 * jj;
                    acc[cl][jj] += xr[o]*wv[cl*8]     + xr[o+1]*wv[cl*8+1]
                                 + xr[o+2]*wv[cl*8+2] + xr[o+3]*wv[cl*8+3]
                                 + xr[o+4]*wv[cl*8+4] + xr[o+5]*wv[cl*8+5]
                                 + xr[o+6]*wv[cl*8+6] + xr[o+7]*wv[cl*8+7];
                }
            }
        }
    }
    #pragma unroll
    for (int cl = 0; cl < 2; ++cl)
        #pragma unroll
        for (int jj = 0; jj < 4; ++jj)
            acc[cl][jj] += __shfl_xor(acc[cl][jj], 1);

    const float o0 = eh ? acc[1][0] : acc[0][0];
    const float o1 = eh ? acc[1][1] : acc[0][1];
    const float o2 = eh ? acc[1][2] : acc[0][2];
    const float o3 = eh ? acc[1][3] : acc[0][3];
    *(float4*)(u1 + (size_t)t * 16384 + n * 256 + (2 * cp + eh) * 64 + i * 8 + jh * 4) =
        make_float4(o0, o1, o2, o3);
}

// ---------------- kf: fused scan1 + conv2 + scan2 + dense ----------------
// 64 blocks x 256 thr, block = batch n. 8 t/round, 13 rounds, 3 lgkm-barriers.
// Hazard proof for 3 barriers, single buffer: any wave's phase-P(rd+1) write
// can only start after ALL waves passed the barrier preceding it, which
// program-order postdates every other wave's conflicting phase-P(rd) access.
__global__ __launch_bounds__(256) void kf(const float* __restrict__ u1,
        const float* __restrict__ wl2g, const float* __restrict__ lw,
        float* __restrict__ out) {
    __shared__ __align__(16) float ls1[8 * 660];   // 21.1 KB
    __shared__ __align__(16) float ls2[8 * 132];   //  4.2 KB
    __shared__ __align__(16) float wl[544];
    const int tid = threadIdx.x, n = blockIdx.x;
    const int wave = tid >> 6, l64 = tid & 63;
    const int sub = tid >> 5, l = tid & 31;
    const float a = DECAY;

    if (tid < 136) *(float4*)(wl + 4 * tid) = *(const float4*)(wl2g + 4 * tid);
    for (int m = tid; m < 1320; m += 256)
        *(float4*)(ls1 + 4 * m) = make_float4(0.f, 0.f, 0.f, 0.f);

    // scan1: thread = neuron (c,row,col) = tid
    const int cs = tid >> 6, rowi = (tid >> 3) & 7, col = tid & 7;
    const int pr1 = (((rowi + 1) & 1) * 5) + ((rowi + 1) >> 1);
    const int woff = cs * 160 + pr1 * 16 + 4 + col;
    const float* up = u1 + n * 256 + tid;

    // conv2 thread mapping (verbatim k3)
    const int c2 = l >> 2, i2 = l & 3;
    const float* wb = wl + c2 * 68;

    const float dw0 = lw[l64], dw1 = lw[64 + l64], dw2 = lw[128 + l64], dw3 = lw[192 + l64];

    float psp = 0.f, rr = 0.f;       // scan1 state
    float psp2 = 0.f, rr2 = 0.f;     // scan2 state (tid<128)

    float vbuf[8];
    #pragma unroll
    for (int k = 0; k < 8; ++k) vbuf[k] = up[(size_t)k * 16384];

    BAR_LGKM();   // ring zero + wl visible

    #pragma unroll 1
    for (int rd = 0; rd < 13; ++rd) {
        const int t0 = rd * 8;
        const int cnt = (rd == 12) ? 4 : 8;

        // --- P1: scan1 advance + publish; issue next prefetch (stays in flight) ---
        float sreg[8];
        #pragma unroll
        for (int k = 0; k < 8; ++k) {
            if (k < cnt) {
                psp = a * psp + vbuf[k];
                const float vv = psp - rr;
                const float s = (vv >= 1.f) ? 1.f : 0.f;
                rr = a * (rr + s);
                sreg[k] = s;
            }
        }
        #pragma unroll
        for (int k = 0; k < 8; ++k) {
            const int tt = t0 + 8 + k;
            if (tt < 100) vbuf[k] = up[(size_t)tt * 16384];
        }
        #pragma unroll
        for (int k = 0; k < 8; ++k)
            if (k < cnt) ls1[k * 660 + woff] = sreg[k];
        BAR_LGKM();

        // --- P2: conv2, slot sub (verbatim k3 body) ---
        if (sub < cnt) {
            const float* tb = ls1 + sub * 660 + i2 * 16;
            float acc[4] = {0.f, 0.f, 0.f, 0.f};
            #pragma unroll
            for (int cin = 0; cin < 4; ++cin) {
                #pragma unroll
                for (int e = 0; e < 4; ++e) {
                    const int C = cin * 160 + ((e & 1) * 5 + (e >> 1)) * 16;
                    float xr[16];
                    #pragma unroll
                    for (int b = 0; b < 4; ++b)
                        *(float4*)(xr + 4 * b) = *(const float4*)(tb + C + 4 * b);
                    float wv[4];
                    *(float4*)(wv) = *(const float4*)(wb + cin * 16 + e * 4);
                    #pragma unroll
                    for (int j = 0; j < 4; ++j) {
                        #pragma unroll
                        for (int f = 0; f < 4; ++f)
                            acc[j] += xr[2 * j + f + 3] * wv[f];
                    }
                }
            }
            *(float4*)(ls2 + sub * 132 + c2 * 16 + i2 * 4) =
                make_float4(acc[0], acc[1], acc[2], acc[3]);
        }
        BAR_LGKM();

        // --- P3: scan2 (tid<128), in-place u2 -> s2 ---
        if (tid < 128) {
            #pragma unroll
            for (int k = 0; k < 8; ++k) {
                if (k < cnt) {
                    const float u = ls2[k * 132 + tid];
                    psp2 = a * psp2 + u;
                    const float vv = psp2 - rr2;
                    const float s = (vv >= 1.f) ? 1.f : 0.f;
                    rr2 = a * (rr2 + s);
                    ls2[k * 132 + tid] = s;
                }
            }
        }
        BAR_LGKM();

        // --- P4: dense, wave handles slots wave and wave+4 (exact tree) ---
        #pragma unroll
        for (int h = 0; h < 2; ++h) {
            const int ss = wave + 4 * h;
            if (ss < cnt) {
                const float sa = ls2[ss * 132 + l64];
                const float sb = ls2[ss * 132 + 64 + l64];
                float a0 = sa * dw0 + sb * dw1;
                float a1 = sa * dw2 + sb * dw3;
                #pragma unroll
                for (int off = 32; off > 0; off >>= 1) {
                    a0 += __shfl_down(a0, off);
                    a1 += __shfl_down(a1, off);
                }
                if (l64 == 0) {
                    const int tt = t0 + ss;
                    out[n * 200 + tt * 2]     = a0;
                    out[n * 200 + tt * 2 + 1] = a1;
                }
            }
        }
        // no barrier here: next round's first conflicting write (P2's ls2)
        // is gated by the P1->P2 barrier, which postdates P4 everywhere.
    }
}

extern "C" void kernel_launch(void* const* d_in, const int* in_sizes, int n_in,
                              void* d_out, int out_size, void* d_ws, size_t ws_size,
                              hipStream_t stream) {
    const float* x   = (const float*)d_in[0];
    const float* w1  = (const float*)d_in[1];
    const float* w2  = (const float*)d_in[2];
    const float* lw  = (const float*)d_in[3];
    const float* wp1 = (const float*)d_in[4];
    const float* wp2 = (const float*)d_in[5];

    float* u1  = (float*)d_ws;           // 1,638,400 floats
    float* wl1 = u1 + 1638400;           //       512 floats
    float* wl2 = wl1 + 512;              //       544 floats
    float* out = (float*)d_out;          // (64,100,2)

    k0_fold<<<1, 128, 0, stream>>>(w1, w2, wp1, wp2, wl1, wl2);
    k1<<<6400, 64, 0, stream>>>(x, wl1, u1);
    kf<<<64, 256, 0, stream>>>(u1, wl2, lw, out);
}

// Round 10
// 140.729 us; speedup vs baseline: 1.0187x; 1.0187x over previous
//
#include <hip/hip_runtime.h>

// SLAYER SNN forward, MI355X. Round 10.
// vs R9: kf split 64 -> 128 blocks (batch-n x c2-half): conv2/scan2/dense
//   halved per block (scan1 duplicated, ~free); dense = two 64-wide partial
//   trees joined by atomicAdd (2 commutative contributions -> deterministic).
//   conv2 weights preloaded into 16 VGPR float4 (no LDS weight reads); tile
//   pad shifted so each row read is 3 ds_read_b128 (was 4): 80 -> 48 LDS
//   instr per slot-thread. k0 also zeroes out (atomic target), grid 100x128.
// k1 unchanged from R9. Spike arithmetic bit-identical everywhere; only the
// terminal dense sum is re-associated (error ~1e-6, no feedback into spikes).

#define DECAY 0.9048374180359595f   // exp(-1/10)

#define BAR_LGKM() asm volatile("s_waitcnt lgkmcnt(0)\n\ts_barrier" ::: "memory")
#define FENCE_LGKM() asm volatile("s_waitcnt lgkmcnt(0)" ::: "memory")

// ---------------- k0: fold weights + zero out ----------------
// wl1[(cin*8 + e)*32 + c*8 + f], e,f in 0..7  (512 floats)
// wl2[c2*68 + cin*16 + e*4 + f]               (544 floats incl. pads)
// grid 100 x 128: block 0 folds; all blocks zero out[12800].
__global__ __launch_bounds__(128) void k0_fold(const float* __restrict__ w1,
        const float* __restrict__ w2, const float* __restrict__ wp1,
        const float* __restrict__ wp2, float* __restrict__ wl1,
        float* __restrict__ wl2, float* __restrict__ out) {
    const int tid = threadIdx.x;
    out[blockIdx.x * 128 + tid] = 0.f;
    if (blockIdx.x != 0) return;
    const float p1 = wp1[0], p2 = wp2[0];
    for (int idx = tid; idx < 512; idx += 128) {
        const int f = idx & 7, c = (idx >> 3) & 3, e = (idx >> 5) & 7, cin = idx >> 8;
        const int cc = c * 2 + cin;
        int alo = e - 3; if (alo < 0) alo = 0;
        int ahi = e;     if (ahi > 4) ahi = 4;
        int blo = f - 3; if (blo < 0) blo = 0;
        int bhi = f;     if (bhi > 4) bhi = 4;
        float s = 0.f;
        for (int a = alo; a <= ahi; ++a)
            for (int b = blo; b <= bhi; ++b)
                s += w1[cc * 25 + a * 5 + b];
        wl1[(cin * 8 + e) * 32 + c * 8 + f] = s * p1;
    }
    for (int idx = tid; idx < 512; idx += 128) {
        const int c2 = idx & 7, f = (idx >> 3) & 3, e = (idx >> 5) & 3, cin = idx >> 7;
        int alo = e - 1; if (alo < 0) alo = 0;
        int ahi = e;     if (ahi > 2) ahi = 2;
        int blo = f - 1; if (blo < 0) blo = 0;
        int bhi = f;     if (bhi > 2) bhi = 2;
        float s = 0.f;
        for (int aa = alo; aa <= ahi; ++aa)
            for (int bb = blo; bb <= bhi; ++bb)
                s += w2[((c2 * 4 + cin) * 3 + aa) * 3 + bb];
        wl2[c2 * 68 + cin * 16 + e * 4 + f] = s * p2;
    }
}

// ---------------- k1: conv1+pool1, 8x8-tap stride-4 (R9, unchanged) ----------------
__global__ __launch_bounds__(64) void k1(const float* __restrict__ x,
        const float* __restrict__ wg, float* __restrict__ u1) {
    __shared__ __align__(16) float xs[2 * 1296];
    __shared__ __align__(16) float wl[512];
    const int lane = threadIdx.x;
    const int frame = blockIdx.x;                  // = n*100 + t (x is n-major)
    const int n = frame / 100, t = frame % 100;

    *(float4*)(wl + 4 * lane)       = *(const float4*)(wg + 4 * lane);
    *(float4*)(wl + 256 + 4 * lane) = *(const float4*)(wg + 256 + 4 * lane);

    #pragma unroll
    for (int m0 = 0; m0 < 128; m0 += 64) {
        const int m = m0 + lane;
        if (m < 72) {
            const int cin = m / 36, rem = m % 36;
            const int rr = rem / 9, q4 = rem % 9;
            const int pr = (rr == 0) ? 0 : (rr == 1) ? 9 : (rr == 2) ? 26 : 35;
            *(float4*)(xs + cin * 1296 + pr * 36 + q4 * 4) = make_float4(0.f, 0.f, 0.f, 0.f);
        }
    }
    #pragma unroll
    for (int m0 = 0; m0 < 192; m0 += 64) {
        const int m = m0 + lane;
        if (m < 144) {
            const int cin = m / 72, rem = m % 72;
            const int side = rem & 1, pr = rem >> 1;
            *(float2*)(xs + cin * 1296 + pr * 36 + side * 34) = make_float2(0.f, 0.f);
        }
    }
    const float4* xg = (const float4*)(x + (size_t)frame * 2048);
    #pragma unroll
    for (int q = 0; q < 8; ++q) {
        const int m = q * 64 + lane;
        const float4 v = xg[m];
        const int li = 4 * m;
        const int cin = li >> 10, row = (li >> 5) & 31, col = li & 31;
        const int r = row + 2;
        const int pr = (r & 3) * 9 + (r >> 2);
        float* d = xs + cin * 1296 + pr * 36 + col + 2;
        *(float2*)(d)     = make_float2(v.x, v.y);
        *(float2*)(d + 2) = make_float2(v.z, v.w);
    }
    FENCE_LGKM();

    const int cp = lane >> 5;
    const int i  = (lane >> 2) & 7;
    const int jh = (lane >> 1) & 1;
    const int eh = lane & 1;

    float acc[2][4] = {{0.f, 0.f, 0.f, 0.f}, {0.f, 0.f, 0.f, 0.f}};
    const float* tb = xs + (i + eh) * 36 + jh * 16;
    #pragma unroll
    for (int cin = 0; cin < 2; ++cin) {
        #pragma unroll
        for (int et = 0; et < 4; ++et) {
            const int ro = cin * 1296 + et * 9 * 36;
            float xr[20];
            #pragma unroll
            for (int b = 0; b < 5; ++b)
                *(float4*)(xr + 4 * b) = *(const float4*)(tb + ro + 4 * b);
            float wv[16];
            const float* wp = wl + (cin * 8 + eh * 4 + et) * 32 + cp * 16;
            #pragma unroll
            for (int q = 0; q < 4; ++q)
                *(float4*)(wv + 4 * q) = *(const float4*)(wp + 4 * q);
            #pragma unroll
            for (int cl = 0; cl < 2; ++cl) {
                #pragma unroll
                for (int jj = 0; jj < 4; ++jj) {
                    const int o = 4 * jj;
                    acc[cl][jj] += xr[o]*wv[cl*8]     + xr[o+1]*wv[cl*8+1]
                                 + xr[o+2]*wv[cl*8+2] + xr[o+3]*wv[cl*8+3]
                                 + xr[o+4]*wv[cl*8+4] + xr[o+5]*wv[cl*8+5]
                                 + xr[o+6]*wv[cl*8+6] + xr[o+7]*wv[cl*8+7];
                }
            }
        }
    }
    #pragma unroll
    for (int cl = 0; cl < 2; ++cl)
        #pragma unroll
        for (int jj = 0; jj < 4; ++jj)
            acc[cl][jj] += __shfl_xor(acc[cl][jj], 1);

    const float o0 = eh ? acc[1][0] : acc[0][0];
    const float o1 = eh ? acc[1][1] : acc[0][1];
    const float o2 = eh ? acc[1][2] : acc[0][2];
    const float o3 = eh ? acc[1][3] : acc[0][3];
    *(float4*)(u1 + (size_t)t * 16384 + n * 256 + (2 * cp + eh) * 64 + i * 8 + jh * 4) =
        make_float4(o0, o1, o2, o3);
}

// ---------------- kf: fused scan1 + conv2(half) + scan2 + dense(partial) ----------------
// grid 128 x 256: block = (n, h) with n = bid>>1, h = bid&1 (c2 half).
// ls1: 8 slots x 660 (cin*160 + perm-row*16 + phys-col), perm(r)=(r&1)*5+(r>>1),
//      logical col C at phys C+1 (so conv2 rows = 3 aligned b128 over phys 0..11).
// ls2: 8 slots x 68 (local c2l*16 + pos), u2 then s2 in place.
// conv2 weights: 16 float4 in VGPRs, loaded once from global (L2-broadcast).
// dense: partial 64-wide shuffle tree per half; atomicAdd (2 contributions,
// commutative -> deterministic) into pre-zeroed out.
__global__ __launch_bounds__(256) void kf(const float* __restrict__ u1,
        const float* __restrict__ wl2g, const float* __restrict__ lw,
        float* __restrict__ out) {
    __shared__ __align__(16) float ls1[8 * 660];   // 21.1 KB
    __shared__ __align__(16) float ls2[8 * 68];    //  2.2 KB
    const int tid = threadIdx.x;
    const int n = blockIdx.x >> 1, h = blockIdx.x & 1;
    const int wave = tid >> 6, l64 = tid & 63;
    const float a = DECAY;

    for (int m = tid; m < 1320; m += 256)
        *(float4*)(ls1 + 4 * m) = make_float4(0.f, 0.f, 0.f, 0.f);

    // scan1: thread = u1 neuron (c,row,col) = tid
    const int cs = tid >> 6, rowi = (tid >> 3) & 7, col = tid & 7;
    const int pr1 = (((rowi + 1) & 1) * 5) + ((rowi + 1) >> 1);
    const int woff = cs * 160 + pr1 * 16 + 1 + col;
    const float* up = u1 + n * 256 + tid;

    // conv2 mapping: tid<128 active; sub = slot, l16 -> (c2 local, i2)
    const int sub = tid >> 4, l16 = tid & 15;
    const int c2l = l16 >> 2, i2 = l16 & 3;
    const int c2g = h * 4 + c2l;

    // preload this thread's conv2 weights: wreg[cin*4+e] = taps f0..3
    float4 wreg[16];
    {
        const float* wbase = wl2g + c2g * 68;
        #pragma unroll
        for (int q = 0; q < 16; ++q)
            wreg[q] = *(const float4*)(wbase + (q >> 2) * 16 + (q & 3) * 4);
    }

    // dense weights for this half (local neuron l64 -> global h*64+l64)
    const float dw0 = lw[h * 64 + l64];
    const float dw1 = lw[128 + h * 64 + l64];

    float psp = 0.f, rr = 0.f;       // scan1 state
    float psp2 = 0.f, rr2 = 0.f;     // scan2 state (tid<64)

    float vbuf[8];
    #pragma unroll
    for (int k = 0; k < 8; ++k) vbuf[k] = up[(size_t)k * 16384];

    BAR_LGKM();   // ring zero visible

    #pragma unroll 1
    for (int rd = 0; rd < 13; ++rd) {
        const int t0 = rd * 8;
        const int cnt = (rd == 12) ? 4 : 8;

        // --- P1: scan1 advance + publish; next prefetch stays in flight ---
        float sreg[8];
        #pragma unroll
        for (int k = 0; k < 8; ++k) {
            if (k < cnt) {
                psp = a * psp + vbuf[k];
                const float vv = psp - rr;
                const float s = (vv >= 1.f) ? 1.f : 0.f;
                rr = a * (rr + s);
                sreg[k] = s;
            }
        }
        #pragma unroll
        for (int k = 0; k < 8; ++k) {
            const int tt = t0 + 8 + k;
            if (tt < 100) vbuf[k] = up[(size_t)tt * 16384];
        }
        #pragma unroll
        for (int k = 0; k < 8; ++k)
            if (k < cnt) ls1[k * 660 + woff] = sreg[k];
        BAR_LGKM();

        // --- P2: conv2 for this c2-half, slot sub ---
        if (tid < 128 && sub < cnt) {
            const float* tb = ls1 + sub * 660 + i2 * 16;
            float acc[4] = {0.f, 0.f, 0.f, 0.f};
            #pragma unroll
            for (int cin = 0; cin < 4; ++cin) {
                #pragma unroll
                for (int e = 0; e < 4; ++e) {
                    const int C = cin * 160 + ((e & 1) * 5 + (e >> 1)) * 16;
                    float xr[12];
                    #pragma unroll
                    for (int b = 0; b < 3; ++b)
                        *(float4*)(xr + 4 * b) = *(const float4*)(tb + C + 4 * b);
                    const float4 wf = wreg[cin * 4 + e];
                    #pragma unroll
                    for (int j = 0; j < 4; ++j) {
                        acc[j] += xr[2 * j]     * wf.x;
                        acc[j] += xr[2 * j + 1] * wf.y;
                        acc[j] += xr[2 * j + 2] * wf.z;
                        acc[j] += xr[2 * j + 3] * wf.w;
                    }
                }
            }
            *(float4*)(ls2 + sub * 68 + c2l * 16 + i2 * 4) =
                make_float4(acc[0], acc[1], acc[2], acc[3]);
        }
        BAR_LGKM();

        // --- P3: scan2 (tid<64 = this half's 64 u2 neurons), in-place ---
        if (tid < 64) {
            #pragma unroll
            for (int k = 0; k < 8; ++k) {
                if (k < cnt) {
                    const float u = ls2[k * 68 + tid];
                    psp2 = a * psp2 + u;
                    const float vv = psp2 - rr2;
                    const float s = (vv >= 1.f) ? 1.f : 0.f;
                    rr2 = a * (rr2 + s);
                    ls2[k * 68 + tid] = s;
                }
            }
        }
        BAR_LGKM();

        // --- P4: dense partial (64-wide tree), atomicAdd into out ---
        #pragma unroll
        for (int hh = 0; hh < 2; ++hh) {
            const int ss = wave + 4 * hh;
            if (ss < cnt) {
                const float sa = ls2[ss * 68 + l64];
                float a0 = sa * dw0;
                float a1 = sa * dw1;
                #pragma unroll
                for (int off = 32; off > 0; off >>= 1) {
                    a0 += __shfl_down(a0, off);
                    a1 += __shfl_down(a1, off);
                }
                if (l64 == 0) {
                    const int tt = t0 + ss;
                    atomicAdd(&out[n * 200 + tt * 2],     a0);
                    atomicAdd(&out[n * 200 + tt * 2 + 1], a1);
                }
            }
        }
        // no barrier: next round's conflicting writes are gated by P1->P2 barrier
    }
}

extern "C" void kernel_launch(void* const* d_in, const int* in_sizes, int n_in,
                              void* d_out, int out_size, void* d_ws, size_t ws_size,
                              hipStream_t stream) {
    const float* x   = (const float*)d_in[0];
    const float* w1  = (const float*)d_in[1];
    const float* w2  = (const float*)d_in[2];
    const float* lw  = (const float*)d_in[3];
    const float* wp1 = (const float*)d_in[4];
    const float* wp2 = (const float*)d_in[5];

    float* u1  = (float*)d_ws;           // 1,638,400 floats
    float* wl1 = u1 + 1638400;           //       512 floats
    float* wl2 = wl1 + 512;              //       544 floats
    float* out = (float*)d_out;          // (64,100,2) = 12800 floats

    k0_fold<<<100, 128, 0, stream>>>(w1, w2, wp1, wp2, wl1, wl2, out);
    k1<<<6400, 64, 0, stream>>>(x, wl1, u1);
    kf<<<128, 256, 0, stream>>>(u1, wl2, lw, out);
}

// Round 11
// 123.908 us; speedup vs baseline: 1.1570x; 1.1358x over previous
//
#include <hip/hip_runtime.h>

// SLAYER SNN forward, MI355X. Round 11.
// vs R10 (kf was latency-pinned at ~8.9k cyc/round regardless of work):
//   kf: 16 t-slots/round (7 rounds, was 13), 2 barriers/round (was 3) via
//       wave0-only scan2+dense tail with intra-wave fence; c2-quarter split
//       (grid 256): P2 uses all 256 threads (2 j-outputs each, b128+b64 row
//       reads). Dense = 4 atomic partials/output (terminal reassociation,
//       ~1e-6). Spike arithmetic bit-identical to R10 (scan1/conv2/scan2).
// k0: fold weights + zero out (atomic target). k1: unchanged R9.

#define DECAY 0.9048374180359595f   // exp(-1/10)

#define BAR_LGKM() asm volatile("s_waitcnt lgkmcnt(0)\n\ts_barrier" ::: "memory")
#define FENCE_LGKM() asm volatile("s_waitcnt lgkmcnt(0)" ::: "memory")

// ---------------- k0: fold weights + zero out ----------------
// wl1[(cin*8 + e)*32 + c*8 + f]; wl2[c2*68 + cin*16 + e*4 + f]
__global__ __launch_bounds__(128) void k0_fold(const float* __restrict__ w1,
        const float* __restrict__ w2, const float* __restrict__ wp1,
        const float* __restrict__ wp2, float* __restrict__ wl1,
        float* __restrict__ wl2, float* __restrict__ out) {
    const int tid = threadIdx.x;
    out[blockIdx.x * 128 + tid] = 0.f;
    if (blockIdx.x != 0) return;
    const float p1 = wp1[0], p2 = wp2[0];
    for (int idx = tid; idx < 512; idx += 128) {
        const int f = idx & 7, c = (idx >> 3) & 3, e = (idx >> 5) & 7, cin = idx >> 8;
        const int cc = c * 2 + cin;
        int alo = e - 3; if (alo < 0) alo = 0;
        int ahi = e;     if (ahi > 4) ahi = 4;
        int blo = f - 3; if (blo < 0) blo = 0;
        int bhi = f;     if (bhi > 4) bhi = 4;
        float s = 0.f;
        for (int a = alo; a <= ahi; ++a)
            for (int b = blo; b <= bhi; ++b)
                s += w1[cc * 25 + a * 5 + b];
        wl1[(cin * 8 + e) * 32 + c * 8 + f] = s * p1;
    }
    for (int idx = tid; idx < 512; idx += 128) {
        const int c2 = idx & 7, f = (idx >> 3) & 3, e = (idx >> 5) & 3, cin = idx >> 7;
        int alo = e - 1; if (alo < 0) alo = 0;
        int ahi = e;     if (ahi > 2) ahi = 2;
        int blo = f - 1; if (blo < 0) blo = 0;
        int bhi = f;     if (bhi > 2) bhi = 2;
        float s = 0.f;
        for (int aa = alo; aa <= ahi; ++aa)
            for (int bb = blo; bb <= bhi; ++bb)
                s += w2[((c2 * 4 + cin) * 3 + aa) * 3 + bb];
        wl2[c2 * 68 + cin * 16 + e * 4 + f] = s * p2;
    }
}

// ---------------- k1: conv1+pool1, 8x8-tap stride-4 (R9, unchanged) ----------------
__global__ __launch_bounds__(64) void k1(const float* __restrict__ x,
        const float* __restrict__ wg, float* __restrict__ u1) {
    __shared__ __align__(16) float xs[2 * 1296];
    __shared__ __align__(16) float wl[512];
    const int lane = threadIdx.x;
    const int frame = blockIdx.x;                  // = n*100 + t (x is n-major)
    const int n = frame / 100, t = frame % 100;

    *(float4*)(wl + 4 * lane)       = *(const float4*)(wg + 4 * lane);
    *(float4*)(wl + 256 + 4 * lane) = *(const float4*)(wg + 256 + 4 * lane);

    #pragma unroll
    for (int m0 = 0; m0 < 128; m0 += 64) {
        const int m = m0 + lane;
        if (m < 72) {
            const int cin = m / 36, rem = m % 36;
            const int rr = rem / 9, q4 = rem % 9;
            const int pr = (rr == 0) ? 0 : (rr == 1) ? 9 : (rr == 2) ? 26 : 35;
            *(float4*)(xs + cin * 1296 + pr * 36 + q4 * 4) = make_float4(0.f, 0.f, 0.f, 0.f);
        }
    }
    #pragma unroll
    for (int m0 = 0; m0 < 192; m0 += 64) {
        const int m = m0 + lane;
        if (m < 144) {
            const int cin = m / 72, rem = m % 72;
            const int side = rem & 1, pr = rem >> 1;
            *(float2*)(xs + cin * 1296 + pr * 36 + side * 34) = make_float2(0.f, 0.f);
        }
    }
    const float4* xg = (const float4*)(x + (size_t)frame * 2048);
    #pragma unroll
    for (int q = 0; q < 8; ++q) {
        const int m = q * 64 + lane;
        const float4 v = xg[m];
        const int li = 4 * m;
        const int cin = li >> 10, row = (li >> 5) & 31, col = li & 31;
        const int r = row + 2;
        const int pr = (r & 3) * 9 + (r >> 2);
        float* d = xs + cin * 1296 + pr * 36 + col + 2;
        *(float2*)(d)     = make_float2(v.x, v.y);
        *(float2*)(d + 2) = make_float2(v.z, v.w);
    }
    FENCE_LGKM();

    const int cp = lane >> 5;
    const int i  = (lane >> 2) & 7;
    const int jh = (lane >> 1) & 1;
    const int eh = lane & 1;

    float acc[2][4] = {{0.f, 0.f, 0.f, 0.f}, {0.f, 0.f, 0.f, 0.f}};
    const float* tb = xs + (i + eh) * 36 + jh * 16;
    #pragma unroll
    for (int cin = 0; cin < 2; ++cin) {
        #pragma unroll
        for (int et = 0; et < 4; ++et) {
            const int ro = cin * 1296 + et * 9 * 36;
            float xr[20];
            #pragma unroll
            for (int b = 0; b < 5; ++b)
                *(float4*)(xr + 4 * b) = *(const float4*)(tb + ro + 4 * b);
            float wv[16];
            const float* wp = wl + (cin * 8 + eh * 4 + et) * 32 + cp * 16;
            #pragma unroll
            for (int q = 0; q < 4; ++q)
                *(float4*)(wv + 4 * q) = *(const float4*)(wp + 4 * q);
            #pragma unroll
            for (int cl = 0; cl < 2; ++cl) {
                #pragma unroll
                for (int jj = 0; jj < 4; ++jj) {
                    const int o = 4 * jj;
                    acc[cl][jj] += xr[o]*wv[cl*8]     + xr[o+1]*wv[cl*8+1]
                                 + xr[o+2]*wv[cl*8+2] + xr[o+3]*wv[cl*8+3]
                                 + xr[o+4]*wv[cl*8+4] + xr[o+5]*wv[cl*8+5]
                                 + xr[o+6]*wv[cl*8+6] + xr[o+7]*wv[cl*8+7];
                }
            }
        }
    }
    #pragma unroll
    for (int cl = 0; cl < 2; ++cl)
        #pragma unroll
        for (int jj = 0; jj < 4; ++jj)
            acc[cl][jj] += __shfl_xor(acc[cl][jj], 1);

    const float o0 = eh ? acc[1][0] : acc[0][0];
    const float o1 = eh ? acc[1][1] : acc[0][1];
    const float o2 = eh ? acc[1][2] : acc[0][2];
    const float o3 = eh ? acc[1][3] : acc[0][3];
    *(float4*)(u1 + (size_t)t * 16384 + n * 256 + (2 * cp + eh) * 64 + i * 8 + jh * 4) =
        make_float4(o0, o1, o2, o3);
}

// ---------------- kf: fused scan1 + conv2(qtr) + scan2 + dense(partial) ----------------
// grid 256 x 256: block = (n, qtr), n = bid>>2, qtr = bid&3 (c2 pair 2qtr,2qtr+1).
// ls1: 16 slots x 660 (cin*160 + perm-row*16 + phys col), perm(r)=(r&1)*5+(r>>1),
//      logical col C at phys C+1 (halos zero). ls2: 16 slots x 36 (c2l*16+pos).
// Per round (16 t): P1 all-wave scan1+publish+prefetch | BAR |
//                   P2 all-wave conv2 (thread = slot,c2l,i2,jh -> 2 j-outputs) | BAR |
//                   wave0 tail: scan2 (lanes<32) + fence + dense partial + atomicAdd;
//                   waves 1-3 roll straight into next P1.
__global__ __launch_bounds__(256) void kf(const float* __restrict__ u1,
        const float* __restrict__ wl2g, const float* __restrict__ lw,
        float* __restrict__ out) {
    __shared__ __align__(16) float ls1[16 * 660];  // 42.2 KB
    __shared__ __align__(16) float ls2[16 * 36];   //  2.3 KB
    const int tid = threadIdx.x;
    const int n = blockIdx.x >> 2, qtr = blockIdx.x & 3;
    const int wave = tid >> 6, l64 = tid & 63;
    const float a = DECAY;

    for (int m = tid; m < 2640; m += 256)
        *(float4*)(ls1 + 4 * m) = make_float4(0.f, 0.f, 0.f, 0.f);

    // scan1: thread = u1 neuron (c,row,col) = tid
    const int cs = tid >> 6, rowi = (tid >> 3) & 7, col = tid & 7;
    const int pr1 = (((rowi + 1) & 1) * 5) + ((rowi + 1) >> 1);
    const int woff = cs * 160 + pr1 * 16 + 1 + col;
    const float* up = u1 + n * 256 + tid;

    // P2: thread = (slot, c2l, i2, jh); 2 j-outputs (j = 2jh, 2jh+1)
    const int sub = tid >> 4, l16 = tid & 15;
    const int c2l = l16 >> 3, i2 = (l16 >> 1) & 3, jhp = l16 & 1;
    const int c2g = qtr * 2 + c2l;

    float4 wreg[16];   // [cin*4+e] = folded taps f0..3 for this thread's c2
    {
        const float* wbase = wl2g + c2g * 68;
        #pragma unroll
        for (int q = 0; q < 16; ++q)
            wreg[q] = *(const float4*)(wbase + (q >> 2) * 16 + (q & 3) * 4);
    }

    // dense partials (wave0): lane -> slot = l64>>2, idx = l64&3; neurons idx*8..+7
    float dwA[8], dwB[8];
    {
        const int idx = l64 & 3;
        #pragma unroll
        for (int m = 0; m < 8; ++m) {
            dwA[m] = lw[qtr * 32 + idx * 8 + m];
            dwB[m] = lw[128 + qtr * 32 + idx * 8 + m];
        }
    }

    float psp = 0.f, rr = 0.f;       // scan1 state (all threads)
    float psp2 = 0.f, rr2 = 0.f;     // scan2 state (wave0 lanes<32)

    float vbuf[16];
    #pragma unroll
    for (int k = 0; k < 16; ++k) vbuf[k] = up[(size_t)k * 16384];

    BAR_LGKM();   // ls1 zero visible

    #pragma unroll 1
    for (int rd = 0; rd < 7; ++rd) {
        const int t0 = rd * 16;
        const int cnt = (rd == 6) ? 4 : 16;

        // --- P1: scan1 advance + publish; reissue prefetch (stays in flight) ---
        float sreg[16];
        #pragma unroll
        for (int k = 0; k < 16; ++k) {
            if (k < cnt) {
                psp = a * psp + vbuf[k];
                const float vv = psp - rr;
                const float s = (vv >= 1.f) ? 1.f : 0.f;
                rr = a * (rr + s);
                sreg[k] = s;
            }
        }
        #pragma unroll
        for (int k = 0; k < 16; ++k) {
            const int tt = t0 + 16 + k;
            if (tt < 100) vbuf[k] = up[(size_t)tt * 16384];
        }
        #pragma unroll
        for (int k = 0; k < 16; ++k)
            if (k < cnt) ls1[k * 660 + woff] = sreg[k];
        BAR_LGKM();

        // --- P2: conv2, all 256 threads (2 outputs each) ---
        if (sub < cnt) {
            const float* tb = ls1 + sub * 660 + i2 * 16 + 4 * jhp;
            float acc0 = 0.f, acc1 = 0.f;
            #pragma unroll
            for (int cin = 0; cin < 4; ++cin) {
                #pragma unroll
                for (int e = 0; e < 4; ++e) {
                    const int C = cin * 160 + ((e & 1) * 5 + (e >> 1)) * 16;
                    float xr[6];
                    *(float4*)(xr)     = *(const float4*)(tb + C);
                    *(float2*)(xr + 4) = *(const float2*)(tb + C + 4);
                    const float4 wf = wreg[cin * 4 + e];
                    acc0 += xr[0] * wf.x; acc0 += xr[1] * wf.y;
                    acc0 += xr[2] * wf.z; acc0 += xr[3] * wf.w;
                    acc1 += xr[2] * wf.x; acc1 += xr[3] * wf.y;
                    acc1 += xr[4] * wf.z; acc1 += xr[5] * wf.w;
                }
            }
            *(float2*)(ls2 + sub * 36 + c2l * 16 + i2 * 4 + 2 * jhp) =
                make_float2(acc0, acc1);
        }
        BAR_LGKM();

        // --- wave0 tail: scan2 + fence + dense partial + atomicAdd ---
        if (wave == 0) {
            if (l64 < 32) {
                #pragma unroll
                for (int k = 0; k < 16; ++k) {
                    if (k < cnt) {
                        const float u = ls2[k * 36 + l64];
                        psp2 = a * psp2 + u;
                        const float vv = psp2 - rr2;
                        const float s = (vv >= 1.f) ? 1.f : 0.f;
                        rr2 = a * (rr2 + s);
                        ls2[k * 36 + l64] = s;
                    }
                }
            }
            FENCE_LGKM();   // intra-wave: scan2 writes visible to dense reads
            const int slot = l64 >> 2, idx = l64 & 3;
            if (slot < cnt) {
                float a0 = 0.f, a1 = 0.f;
                #pragma unroll
                for (int m = 0; m < 8; ++m) {
                    const float s = ls2[slot * 36 + idx * 8 + m];
                    a0 += s * dwA[m];
                    a1 += s * dwB[m];
                }
                a0 += __shfl_down(a0, 2); a0 += __shfl_down(a0, 1);
                a1 += __shfl_down(a1, 2); a1 += __shfl_down(a1, 1);
                if (idx == 0) {
                    const int tt = t0 + slot;
                    atomicAdd(&out[n * 200 + tt * 2],     a0);
                    atomicAdd(&out[n * 200 + tt * 2 + 1], a1);
                }
            }
        }
        // waves 1-3: no tail work; they proceed to next P1 (safe: next ls2
        // writes are behind the next P1-end barrier, which wave0 reaches
        // only after its tail).
    }
}

extern "C" void kernel_launch(void* const* d_in, const int* in_sizes, int n_in,
                              void* d_out, int out_size, void* d_ws, size_t ws_size,
                              hipStream_t stream) {
    const float* x   = (const float*)d_in[0];
    const float* w1  = (const float*)d_in[1];
    const float* w2  = (const float*)d_in[2];
    const float* lw  = (const float*)d_in[3];
    const float* wp1 = (const float*)d_in[4];
    const float* wp2 = (const float*)d_in[5];

    float* u1  = (float*)d_ws;           // 1,638,400 floats
    float* wl1 = u1 + 1638400;           //       512 floats
    float* wl2 = wl1 + 512;              //       544 floats
    float* out = (float*)d_out;          // (64,100,2) = 12800 floats

    k0_fold<<<100, 128, 0, stream>>>(w1, w2, wp1, wp2, wl1, wl2, out);
    k1<<<6400, 64, 0, stream>>>(x, wl1, u1);
    kf<<<256, 256, 0, stream>>>(u1, wl2, lw, out);
}

// Round 12
// 123.895 us; speedup vs baseline: 1.1571x; 1.0001x over previous
//
#include <hip/hip_runtime.h>

// SLAYER SNN forward, MI355X. Round 12.
// vs R11 (single change, clean attribution): kf goes 16 slots x 7 rounds ->
//   32 slots x 4 rounds (3 full + tail-4). Measured model: per-round cost is
//   ~7k cyc fixed (barrier+phase latency at 1 block/CU) + ~250 cyc/slot; fewer
//   rounds is the only lever that has moved kf (R10: work/2 -> no change;
//   R11: rounds/2 -> -17 us). ls1 = 32 slots x 660 = 82.5 KB (1 block/CU,
//   unchanged). P2/dense become 2-pass (16 slots/pass). All summation trees
//   and the 4-partial atomic dense are byte-identical to R11 (absmax 0.0).
// k0 (fold+zero-out) and k1 (R9 conv1) unchanged.

#define DECAY 0.9048374180359595f   // exp(-1/10)

#define BAR_LGKM() asm volatile("s_waitcnt lgkmcnt(0)\n\ts_barrier" ::: "memory")
#define FENCE_LGKM() asm volatile("s_waitcnt lgkmcnt(0)" ::: "memory")

// ---------------- k0: fold weights + zero out ----------------
// wl1[(cin*8 + e)*32 + c*8 + f]; wl2[c2*68 + cin*16 + e*4 + f]
__global__ __launch_bounds__(128) void k0_fold(const float* __restrict__ w1,
        const float* __restrict__ w2, const float* __restrict__ wp1,
        const float* __restrict__ wp2, float* __restrict__ wl1,
        float* __restrict__ wl2, float* __restrict__ out) {
    const int tid = threadIdx.x;
    out[blockIdx.x * 128 + tid] = 0.f;
    if (blockIdx.x != 0) return;
    const float p1 = wp1[0], p2 = wp2[0];
    for (int idx = tid; idx < 512; idx += 128) {
        const int f = idx & 7, c = (idx >> 3) & 3, e = (idx >> 5) & 7, cin = idx >> 8;
        const int cc = c * 2 + cin;
        int alo = e - 3; if (alo < 0) alo = 0;
        int ahi = e;     if (ahi > 4) ahi = 4;
        int blo = f - 3; if (blo < 0) blo = 0;
        int bhi = f;     if (bhi > 4) bhi = 4;
        float s = 0.f;
        for (int a = alo; a <= ahi; ++a)
            for (int b = blo; b <= bhi; ++b)
                s += w1[cc * 25 + a * 5 + b];
        wl1[(cin * 8 + e) * 32 + c * 8 + f] = s * p1;
    }
    for (int idx = tid; idx < 512; idx += 128) {
        const int c2 = idx & 7, f = (idx >> 3) & 3, e = (idx >> 5) & 3, cin = idx >> 7;
        int alo = e - 1; if (alo < 0) alo = 0;
        int ahi = e;     if (ahi > 2) ahi = 2;
        int blo = f - 1; if (blo < 0) blo = 0;
        int bhi = f;     if (bhi > 2) bhi = 2;
        float s = 0.f;
        for (int aa = alo; aa <= ahi; ++aa)
            for (int bb = blo; bb <= bhi; ++bb)
                s += w2[((c2 * 4 + cin) * 3 + aa) * 3 + bb];
        wl2[c2 * 68 + cin * 16 + e * 4 + f] = s * p2;
    }
}

// ---------------- k1: conv1+pool1, 8x8-tap stride-4 (R9, unchanged) ----------------
__global__ __launch_bounds__(64) void k1(const float* __restrict__ x,
        const float* __restrict__ wg, float* __restrict__ u1) {
    __shared__ __align__(16) float xs[2 * 1296];
    __shared__ __align__(16) float wl[512];
    const int lane = threadIdx.x;
    const int frame = blockIdx.x;                  // = n*100 + t (x is n-major)
    const int n = frame / 100, t = frame % 100;

    *(float4*)(wl + 4 * lane)       = *(const float4*)(wg + 4 * lane);
    *(float4*)(wl + 256 + 4 * lane) = *(const float4*)(wg + 256 + 4 * lane);

    #pragma unroll
    for (int m0 = 0; m0 < 128; m0 += 64) {
        const int m = m0 + lane;
        if (m < 72) {
            const int cin = m / 36, rem = m % 36;
            const int rr = rem / 9, q4 = rem % 9;
            const int pr = (rr == 0) ? 0 : (rr == 1) ? 9 : (rr == 2) ? 26 : 35;
            *(float4*)(xs + cin * 1296 + pr * 36 + q4 * 4) = make_float4(0.f, 0.f, 0.f, 0.f);
        }
    }
    #pragma unroll
    for (int m0 = 0; m0 < 192; m0 += 64) {
        const int m = m0 + lane;
        if (m < 144) {
            const int cin = m / 72, rem = m % 72;
            const int side = rem & 1, pr = rem >> 1;
            *(float2*)(xs + cin * 1296 + pr * 36 + side * 34) = make_float2(0.f, 0.f);
        }
    }
    const float4* xg = (const float4*)(x + (size_t)frame * 2048);
    #pragma unroll
    for (int q = 0; q < 8; ++q) {
        const int m = q * 64 + lane;
        const float4 v = xg[m];
        const int li = 4 * m;
        const int cin = li >> 10, row = (li >> 5) & 31, col = li & 31;
        const int r = row + 2;
        const int pr = (r & 3) * 9 + (r >> 2);
        float* d = xs + cin * 1296 + pr * 36 + col + 2;
        *(float2*)(d)     = make_float2(v.x, v.y);
        *(float2*)(d + 2) = make_float2(v.z, v.w);
    }
    FENCE_LGKM();

    const int cp = lane >> 5;
    const int i  = (lane >> 2) & 7;
    const int jh = (lane >> 1) & 1;
    const int eh = lane & 1;

    float acc[2][4] = {{0.f, 0.f, 0.f, 0.f}, {0.f, 0.f, 0.f, 0.f}};
    const float* tb = xs + (i + eh) * 36 + jh * 16;
    #pragma unroll
    for (int cin = 0; cin < 2; ++cin) {
        #pragma unroll
        for (int et = 0; et < 4; ++et) {
            const int ro = cin * 1296 + et * 9 * 36;
            float xr[20];
            #pragma unroll
            for (int b = 0; b < 5; ++b)
                *(float4*)(xr + 4 * b) = *(const float4*)(tb + ro + 4 * b);
            float wv[16];
            const float* wp = wl + (cin * 8 + eh * 4 + et) * 32 + cp * 16;
            #pragma unroll
            for (int q = 0; q < 4; ++q)
                *(float4*)(wv + 4 * q) = *(const float4*)(wp + 4 * q);
            #pragma unroll
            for (int cl = 0; cl < 2; ++cl) {
                #pragma unroll
                for (int jj = 0; jj < 4; ++jj) {
                    const int o = 4 * jj;
                    acc[cl][jj] += xr[o]*wv[cl*8]     + xr[o+1]*wv[cl*8+1]
                                 + xr[o+2]*wv[cl*8+2] + xr[o+3]*wv[cl*8+3]
                                 + xr[o+4]*wv[cl*8+4] + xr[o+5]*wv[cl*8+5]
                                 + xr[o+6]*wv[cl*8+6] + xr[o+7]*wv[cl*8+7];
                }
            }
        }
    }
    #pragma unroll
    for (int cl = 0; cl < 2; ++cl)
        #pragma unroll
        for (int jj = 0; jj < 4; ++jj)
            acc[cl][jj] += __shfl_xor(acc[cl][jj], 1);

    const float o0 = eh ? acc[1][0] : acc[0][0];
    const float o1 = eh ? acc[1][1] : acc[0][1];
    const float o2 = eh ? acc[1][2] : acc[0][2];
    const float o3 = eh ? acc[1][3] : acc[0][3];
    *(float4*)(u1 + (size_t)t * 16384 + n * 256 + (2 * cp + eh) * 64 + i * 8 + jh * 4) =
        make_float4(o0, o1, o2, o3);
}

// ---------------- kf: fused scan1 + conv2(qtr) + scan2 + dense(partial) ----------------
// grid 256 x 256: block = (n, qtr), n = bid>>2, qtr = bid&3 (c2 pair 2qtr,2qtr+1).
// ls1: 32 slots x 660 (cin*160 + perm-row*16 + phys col), perm(r)=(r&1)*5+(r>>1),
//      logical col C at phys C+1 (halos zero). ls2: 32 slots x 36 (c2l*16+pos).
// Per round (32 t): P1 all-wave scan1+publish+prefetch | BAR |
//                   P2 all-wave conv2, 2 passes of 16 slots | BAR |
//                   wave0 tail: scan2 (lanes<32) + fence + dense 2 passes + atomicAdd;
//                   waves 1-3 roll straight into next P1 (race-free, see R11).
__global__ __launch_bounds__(256) void kf(const float* __restrict__ u1,
        const float* __restrict__ wl2g, const float* __restrict__ lw,
        float* __restrict__ out) {
    __shared__ __align__(16) float ls1[32 * 660];  // 82.5 KB
    __shared__ __align__(16) float ls2[32 * 36];   //  4.6 KB
    const int tid = threadIdx.x;
    const int n = blockIdx.x >> 2, qtr = blockIdx.x & 3;
    const int wave = tid >> 6, l64 = tid & 63;
    const float a = DECAY;

    for (int m = tid; m < 5280; m += 256)
        *(float4*)(ls1 + 4 * m) = make_float4(0.f, 0.f, 0.f, 0.f);

    // scan1: thread = u1 neuron (c,row,col) = tid
    const int cs = tid >> 6, rowi = (tid >> 3) & 7, col = tid & 7;
    const int pr1 = (((rowi + 1) & 1) * 5) + ((rowi + 1) >> 1);
    const int woff = cs * 160 + pr1 * 16 + 1 + col;
    const float* up = u1 + n * 256 + tid;

    // P2: thread = (sub-slot, c2l, i2, jh); 2 j-outputs (j = 2jh, 2jh+1)
    const int sub = tid >> 4, l16 = tid & 15;
    const int c2l = l16 >> 3, i2 = (l16 >> 1) & 3, jhp = l16 & 1;
    const int c2g = qtr * 2 + c2l;

    float4 wreg[16];   // [cin*4+e] = folded taps f0..3 for this thread's c2
    {
        const float* wbase = wl2g + c2g * 68;
        #pragma unroll
        for (int q = 0; q < 16; ++q)
            wreg[q] = *(const float4*)(wbase + (q >> 2) * 16 + (q & 3) * 4);
    }

    // dense partials (wave0): lane -> slot = l64>>2 (+16 pass), idx = l64&3
    float dwA[8], dwB[8];
    {
        const int idx = l64 & 3;
        #pragma unroll
        for (int m = 0; m < 8; ++m) {
            dwA[m] = lw[qtr * 32 + idx * 8 + m];
            dwB[m] = lw[128 + qtr * 32 + idx * 8 + m];
        }
    }

    float psp = 0.f, rr = 0.f;       // scan1 state (all threads)
    float psp2 = 0.f, rr2 = 0.f;     // scan2 state (wave0 lanes<32)

    float vbuf[32];
    #pragma unroll
    for (int k = 0; k < 32; ++k) vbuf[k] = up[(size_t)k * 16384];

    BAR_LGKM();   // ls1 zero visible

    #pragma unroll 1
    for (int rd = 0; rd < 4; ++rd) {
        const int t0 = rd * 32;
        const int cnt = (rd == 3) ? 4 : 32;

        // --- P1: scan1 advance + publish; reissue prefetch (stays in flight) ---
        float sreg[32];
        #pragma unroll
        for (int k = 0; k < 32; ++k) {
            if (k < cnt) {
                psp = a * psp + vbuf[k];
                const float vv = psp - rr;
                const float s = (vv >= 1.f) ? 1.f : 0.f;
                rr = a * (rr + s);
                sreg[k] = s;
            }
        }
        #pragma unroll
        for (int k = 0; k < 32; ++k) {
            const int tt = t0 + 32 + k;
            if (tt < 100) vbuf[k] = up[(size_t)tt * 16384];
        }
        #pragma unroll
        for (int k = 0; k < 32; ++k)
            if (k < cnt) ls1[k * 660 + woff] = sreg[k];
        BAR_LGKM();

        // --- P2: conv2, 2 passes x 16 slots, all 256 threads (2 outputs each) ---
        #pragma unroll
        for (int pass = 0; pass < 2; ++pass) {
            const int slot = sub + 16 * pass;
            if (slot < cnt) {
                const float* tb = ls1 + slot * 660 + i2 * 16 + 4 * jhp;
                float acc0 = 0.f, acc1 = 0.f;
                #pragma unroll
                for (int cin = 0; cin < 4; ++cin) {
                    #pragma unroll
                    for (int e = 0; e < 4; ++e) {
                        const int C = cin * 160 + ((e & 1) * 5 + (e >> 1)) * 16;
                        float xr[6];
                        *(float4*)(xr)     = *(const float4*)(tb + C);
                        *(float2*)(xr + 4) = *(const float2*)(tb + C + 4);
                        const float4 wf = wreg[cin * 4 + e];
                        acc0 += xr[0] * wf.x; acc0 += xr[1] * wf.y;
                        acc0 += xr[2] * wf.z; acc0 += xr[3] * wf.w;
                        acc1 += xr[2] * wf.x; acc1 += xr[3] * wf.y;
                        acc1 += xr[4] * wf.z; acc1 += xr[5] * wf.w;
                    }
                }
                *(float2*)(ls2 + slot * 36 + c2l * 16 + i2 * 4 + 2 * jhp) =
                    make_float2(acc0, acc1);
            }
        }
        BAR_LGKM();

        // --- wave0 tail: scan2 + fence + dense partials + atomicAdd ---
        if (wave == 0) {
            if (l64 < 32) {
                #pragma unroll
                for (int k = 0; k < 32; ++k) {
                    if (k < cnt) {
                        const float u = ls2[k * 36 + l64];
                        psp2 = a * psp2 + u;
                        const float vv = psp2 - rr2;
                        const float s = (vv >= 1.f) ? 1.f : 0.f;
                        rr2 = a * (rr2 + s);
                        ls2[k * 36 + l64] = s;
                    }
                }
            }
            FENCE_LGKM();   // intra-wave: scan2 writes visible to dense reads
            #pragma unroll
            for (int pass = 0; pass < 2; ++pass) {
                const int slot = (l64 >> 2) + 16 * pass;
                const int idx = l64 & 3;
                if (slot < cnt) {
                    float a0 = 0.f, a1 = 0.f;
                    #pragma unroll
                    for (int m = 0; m < 8; ++m) {
                        const float s = ls2[slot * 36 + idx * 8 + m];
                        a0 += s * dwA[m];
                        a1 += s * dwB[m];
                    }
                    a0 += __shfl_down(a0, 2); a0 += __shfl_down(a0, 1);
                    a1 += __shfl_down(a1, 2); a1 += __shfl_down(a1, 1);
                    if (idx == 0) {
                        const int tt = t0 + slot;
                        atomicAdd(&out[n * 200 + tt * 2],     a0);
                        atomicAdd(&out[n * 200 + tt * 2 + 1], a1);
                    }
                }
            }
        }
        // waves 1-3: no tail; next round's conflicting ls2 writes are behind
        // the next P1-end barrier, which wave0 reaches only after its tail.
    }
}

extern "C" void kernel_launch(void* const* d_in, const int* in_sizes, int n_in,
                              void* d_out, int out_size, void* d_ws, size_t ws_size,
                              hipStream_t stream) {
    const float* x   = (const float*)d_in[0];
    const float* w1  = (const float*)d_in[1];
    const float* w2  = (const float*)d_in[2];
    const float* lw  = (const float*)d_in[3];
    const float* wp1 = (const float*)d_in[4];
    const float* wp2 = (const float*)d_in[5];

    float* u1  = (float*)d_ws;           // 1,638,400 floats
    float* wl1 = u1 + 1638400;           //       512 floats
    float* wl2 = wl1 + 512;              //       544 floats
    float* out = (float*)d_out;          // (64,100,2) = 12800 floats

    k0_fold<<<100, 128, 0, stream>>>(w1, w2, wp1, wp2, wl1, wl2, out);
    k1<<<6400, 64, 0, stream>>>(x, wl1, u1);
    kf<<<256, 256, 0, stream>>>(u1, wl2, lw, out);
}

// Round 13
// 119.764 us; speedup vs baseline: 1.1971x; 1.0345x over previous
//
#include <hip/hip_runtime.h>

// SLAYER SNN forward, MI355X. Round 13.
// vs R12: kf rewritten round-free — all 100 timesteps resident in LDS.
//   ls1 = 100 compact 260-float slots (104 KB, no halo pad; stride 260 ->
//   <=2-way banks). Boundary taps rebuilt in registers with cndmask selects
//   producing exactly the +0.0 values the old pad reads returned -> conv2
//   FMA tree bit-identical to R12. Scan1 publish = ls1[k*260+tid]. Weights
//   in VGPRs; no LDS zero-init; TWO barriers total (was 2/round x 4 rounds).
//   P2 and dense tail are 7 predicated 16-slot passes; vbuf[100] in regs.
// k0 (fold+zero out) and k1 (R9 conv1) unchanged.

#define DECAY 0.9048374180359595f   // exp(-1/10)

#define BAR_LGKM() asm volatile("s_waitcnt lgkmcnt(0)\n\ts_barrier" ::: "memory")
#define FENCE_LGKM() asm volatile("s_waitcnt lgkmcnt(0)" ::: "memory")

// ---------------- k0: fold weights + zero out ----------------
// wl1[(cin*8 + e)*32 + c*8 + f]; wl2[c2*68 + cin*16 + e*4 + f]
__global__ __launch_bounds__(128) void k0_fold(const float* __restrict__ w1,
        const float* __restrict__ w2, const float* __restrict__ wp1,
        const float* __restrict__ wp2, float* __restrict__ wl1,
        float* __restrict__ wl2, float* __restrict__ out) {
    const int tid = threadIdx.x;
    out[blockIdx.x * 128 + tid] = 0.f;
    if (blockIdx.x != 0) return;
    const float p1 = wp1[0], p2 = wp2[0];
    for (int idx = tid; idx < 512; idx += 128) {
        const int f = idx & 7, c = (idx >> 3) & 3, e = (idx >> 5) & 7, cin = idx >> 8;
        const int cc = c * 2 + cin;
        int alo = e - 3; if (alo < 0) alo = 0;
        int ahi = e;     if (ahi > 4) ahi = 4;
        int blo = f - 3; if (blo < 0) blo = 0;
        int bhi = f;     if (bhi > 4) bhi = 4;
        float s = 0.f;
        for (int a = alo; a <= ahi; ++a)
            for (int b = blo; b <= bhi; ++b)
                s += w1[cc * 25 + a * 5 + b];
        wl1[(cin * 8 + e) * 32 + c * 8 + f] = s * p1;
    }
    for (int idx = tid; idx < 512; idx += 128) {
        const int c2 = idx & 7, f = (idx >> 3) & 3, e = (idx >> 5) & 3, cin = idx >> 7;
        int alo = e - 1; if (alo < 0) alo = 0;
        int ahi = e;     if (ahi > 2) ahi = 2;
        int blo = f - 1; if (blo < 0) blo = 0;
        int bhi = f;     if (bhi > 2) bhi = 2;
        float s = 0.f;
        for (int aa = alo; aa <= ahi; ++aa)
            for (int bb = blo; bb <= bhi; ++bb)
                s += w2[((c2 * 4 + cin) * 3 + aa) * 3 + bb];
        wl2[c2 * 68 + cin * 16 + e * 4 + f] = s * p2;
    }
}

// ---------------- k1: conv1+pool1, 8x8-tap stride-4 (R9, unchanged) ----------------
__global__ __launch_bounds__(64) void k1(const float* __restrict__ x,
        const float* __restrict__ wg, float* __restrict__ u1) {
    __shared__ __align__(16) float xs[2 * 1296];
    __shared__ __align__(16) float wl[512];
    const int lane = threadIdx.x;
    const int frame = blockIdx.x;                  // = n*100 + t (x is n-major)
    const int n = frame / 100, t = frame % 100;

    *(float4*)(wl + 4 * lane)       = *(const float4*)(wg + 4 * lane);
    *(float4*)(wl + 256 + 4 * lane) = *(const float4*)(wg + 256 + 4 * lane);

    #pragma unroll
    for (int m0 = 0; m0 < 128; m0 += 64) {
        const int m = m0 + lane;
        if (m < 72) {
            const int cin = m / 36, rem = m % 36;
            const int rr = rem / 9, q4 = rem % 9;
            const int pr = (rr == 0) ? 0 : (rr == 1) ? 9 : (rr == 2) ? 26 : 35;
            *(float4*)(xs + cin * 1296 + pr * 36 + q4 * 4) = make_float4(0.f, 0.f, 0.f, 0.f);
        }
    }
    #pragma unroll
    for (int m0 = 0; m0 < 192; m0 += 64) {
        const int m = m0 + lane;
        if (m < 144) {
            const int cin = m / 72, rem = m % 72;
            const int side = rem & 1, pr = rem >> 1;
            *(float2*)(xs + cin * 1296 + pr * 36 + side * 34) = make_float2(0.f, 0.f);
        }
    }
    const float4* xg = (const float4*)(x + (size_t)frame * 2048);
    #pragma unroll
    for (int q = 0; q < 8; ++q) {
        const int m = q * 64 + lane;
        const float4 v = xg[m];
        const int li = 4 * m;
        const int cin = li >> 10, row = (li >> 5) & 31, col = li & 31;
        const int r = row + 2;
        const int pr = (r & 3) * 9 + (r >> 2);
        float* d = xs + cin * 1296 + pr * 36 + col + 2;
        *(float2*)(d)     = make_float2(v.x, v.y);
        *(float2*)(d + 2) = make_float2(v.z, v.w);
    }
    FENCE_LGKM();

    const int cp = lane >> 5;
    const int i  = (lane >> 2) & 7;
    const int jh = (lane >> 1) & 1;
    const int eh = lane & 1;

    float acc[2][4] = {{0.f, 0.f, 0.f, 0.f}, {0.f, 0.f, 0.f, 0.f}};
    const float* tb = xs + (i + eh) * 36 + jh * 16;
    #pragma unroll
    for (int cin = 0; cin < 2; ++cin) {
        #pragma unroll
        for (int et = 0; et < 4; ++et) {
            const int ro = cin * 1296 + et * 9 * 36;
            float xr[20];
            #pragma unroll
            for (int b = 0; b < 5; ++b)
                *(float4*)(xr + 4 * b) = *(const float4*)(tb + ro + 4 * b);
            float wv[16];
            const float* wp = wl + (cin * 8 + eh * 4 + et) * 32 + cp * 16;
            #pragma unroll
            for (int q = 0; q < 4; ++q)
                *(float4*)(wv + 4 * q) = *(const float4*)(wp + 4 * q);
            #pragma unroll
            for (int cl = 0; cl < 2; ++cl) {
                #pragma unroll
                for (int jj = 0; jj < 4; ++jj) {
                    const int o = 4 * jj;
                    acc[cl][jj] += xr[o]*wv[cl*8]     + xr[o+1]*wv[cl*8+1]
                                 + xr[o+2]*wv[cl*8+2] + xr[o+3]*wv[cl*8+3]
                                 + xr[o+4]*wv[cl*8+4] + xr[o+5]*wv[cl*8+5]
                                 + xr[o+6]*wv[cl*8+6] + xr[o+7]*wv[cl*8+7];
                }
            }
        }
    }
    #pragma unroll
    for (int cl = 0; cl < 2; ++cl)
        #pragma unroll
        for (int jj = 0; jj < 4; ++jj)
            acc[cl][jj] += __shfl_xor(acc[cl][jj], 1);

    const float o0 = eh ? acc[1][0] : acc[0][0];
    const float o1 = eh ? acc[1][1] : acc[0][1];
    const float o2 = eh ? acc[1][2] : acc[0][2];
    const float o3 = eh ? acc[1][3] : acc[0][3];
    *(float4*)(u1 + (size_t)t * 16384 + n * 256 + (2 * cp + eh) * 64 + i * 8 + jh * 4) =
        make_float4(o0, o1, o2, o3);
}

// ---------------- kf: fused scan1 + conv2(qtr) + scan2 + dense, round-free ----------------
// grid 256 x 256: block = (n, qtr), n = bid>>2, qtr = bid&3 (c2 pair 2qtr,2qtr+1).
// ls1: 100 slots x 260 floats, cell (cin,row,col) at slot*260 + cin*64+row*8+col
//      = slot*260 + tid for the publishing thread (tid bit-decomposes).
// ls2: 100 slots x 36 (c2l*16 + i2*4 + 2jhp + w).
// Boundary taps: read full 8-float row (2 b128), build xr[6] with selects that
// reproduce the old pad-read zeros exactly; out-of-range rows select to 0.0.
__global__ __launch_bounds__(256) void kf(const float* __restrict__ u1,
        const float* __restrict__ wl2g, const float* __restrict__ lw,
        float* __restrict__ out) {
    __shared__ __align__(16) float ls1[100 * 260];  // 104 KB
    __shared__ __align__(16) float ls2[100 * 36];   // 14.4 KB
    const int tid = threadIdx.x;
    const int n = blockIdx.x >> 2, qtr = blockIdx.x & 3;
    const int wave = tid >> 6, l64 = tid & 63;
    const float a = DECAY;

    const float* up = u1 + n * 256 + tid;

    // P2 mapping: thread = (sub, c2l, i2, jhp); 2 j-outputs (j = 2jhp, 2jhp+1)
    const int sub = tid >> 4, l16 = tid & 15;
    const int c2l = l16 >> 3, i2 = (l16 >> 1) & 3, jhp = l16 & 1;
    const int c2g = qtr * 2 + c2l;

    float4 wreg[16];   // [cin*4+e] = folded taps f0..3
    {
        const float* wbase = wl2g + c2g * 68;
        #pragma unroll
        for (int q = 0; q < 16; ++q)
            wreg[q] = *(const float4*)(wbase + (q >> 2) * 16 + (q & 3) * 4);
    }

    // dense partial weights (wave0 lanes): idx = l64&3 -> neurons idx*8..+7
    float dwA[8], dwB[8];
    {
        const int idx = l64 & 3;
        #pragma unroll
        for (int m = 0; m < 8; ++m) {
            dwA[m] = lw[qtr * 32 + idx * 8 + m];
            dwB[m] = lw[128 + qtr * 32 + idx * 8 + m];
        }
    }

    // --- P1: load all 100 u (coalesced, pipelined), scan1, publish ---
    float vbuf[100];
    #pragma unroll
    for (int k = 0; k < 100; ++k) vbuf[k] = up[(size_t)k * 16384];
    {
        float psp = 0.f, rr = 0.f;
        #pragma unroll
        for (int k = 0; k < 100; ++k) {
            psp = a * psp + vbuf[k];
            const float vv = psp - rr;
            const float s = (vv >= 1.f) ? 1.f : 0.f;
            rr = a * (rr + s);
            ls1[k * 260 + tid] = s;
        }
    }
    BAR_LGKM();

    // --- P2: conv2, 7 predicated passes x 16 slots ---
    #pragma unroll 1
    for (int pass = 0; pass < 7; ++pass) {
        const int slot = sub + 16 * pass;
        if (slot < 100) {
            const float* sb = ls1 + slot * 260;
            float acc0 = 0.f, acc1 = 0.f;
            #pragma unroll
            for (int cin = 0; cin < 4; ++cin) {
                #pragma unroll
                for (int e = 0; e < 4; ++e) {
                    const int ri = 2 * i2 + e - 1;            // input row, -1..8
                    const int rc = (ri < 0) ? 0 : (ri > 7 ? 7 : ri);
                    const bool rok = (ri >= 0) && (ri <= 7);
                    float rr8[8];
                    const float* rp = sb + cin * 64 + rc * 8;
                    *(float4*)(rr8)     = *(const float4*)(rp);
                    *(float4*)(rr8 + 4) = *(const float4*)(rp + 4);
                    // xr matches R12's pad reads: jhp=0 -> {0,r0..r4}; jhp=1 -> {r3..r7,0}
                    float xr[6];
                    xr[0] = jhp ? rr8[3] : 0.0f;
                    xr[1] = jhp ? rr8[4] : rr8[0];
                    xr[2] = jhp ? rr8[5] : rr8[1];
                    xr[3] = jhp ? rr8[6] : rr8[2];
                    xr[4] = jhp ? rr8[7] : rr8[3];
                    xr[5] = jhp ? 0.0f   : rr8[4];
                    if (!rok) {
                        #pragma unroll
                        for (int m = 0; m < 6; ++m) xr[m] = 0.0f;
                    }
                    const float4 wf = wreg[cin * 4 + e];
                    acc0 += xr[0] * wf.x; acc0 += xr[1] * wf.y;
                    acc0 += xr[2] * wf.z; acc0 += xr[3] * wf.w;
                    acc1 += xr[2] * wf.x; acc1 += xr[3] * wf.y;
                    acc1 += xr[4] * wf.z; acc1 += xr[5] * wf.w;
                }
            }
            *(float2*)(ls2 + slot * 36 + c2l * 16 + i2 * 4 + 2 * jhp) =
                make_float2(acc0, acc1);
        }
    }
    BAR_LGKM();

    // --- tail (wave0): scan2 in-place, fence, dense partials + atomicAdd ---
    if (wave == 0) {
        if (l64 < 32) {
            float psp2 = 0.f, rr2 = 0.f;
            #pragma unroll
            for (int k = 0; k < 100; ++k) {
                const float u = ls2[k * 36 + l64];
                psp2 = a * psp2 + u;
                const float vv = psp2 - rr2;
                const float s = (vv >= 1.f) ? 1.f : 0.f;
                rr2 = a * (rr2 + s);
                ls2[k * 36 + l64] = s;
            }
        }
        FENCE_LGKM();   // intra-wave: scan2 writes visible to dense reads
        const int idx = l64 & 3;
        #pragma unroll 1
        for (int pass = 0; pass < 7; ++pass) {
            const int slot = (l64 >> 2) + 16 * pass;
            if (slot < 100) {
                float a0 = 0.f, a1 = 0.f;
                #pragma unroll
                for (int m = 0; m < 8; ++m) {
                    const float s = ls2[slot * 36 + idx * 8 + m];
                    a0 += s * dwA[m];
                    a1 += s * dwB[m];
                }
                a0 += __shfl_down(a0, 2); a0 += __shfl_down(a0, 1);
                a1 += __shfl_down(a1, 2); a1 += __shfl_down(a1, 1);
                if (idx == 0) {
                    atomicAdd(&out[n * 200 + slot * 2],     a0);
                    atomicAdd(&out[n * 200 + slot * 2 + 1], a1);
                }
            }
        }
    }
}

extern "C" void kernel_launch(void* const* d_in, const int* in_sizes, int n_in,
                              void* d_out, int out_size, void* d_ws, size_t ws_size,
                              hipStream_t stream) {
    const float* x   = (const float*)d_in[0];
    const float* w1  = (const float*)d_in[1];
    const float* w2  = (const float*)d_in[2];
    const float* lw  = (const float*)d_in[3];
    const float* wp1 = (const float*)d_in[4];
    const float* wp2 = (const float*)d_in[5];

    float* u1  = (float*)d_ws;           // 1,638,400 floats
    float* wl1 = u1 + 1638400;           //       512 floats
    float* wl2 = wl1 + 512;              //       544 floats
    float* out = (float*)d_out;          // (64,100,2) = 12800 floats

    k0_fold<<<100, 128, 0, stream>>>(w1, w2, wp1, wp2, wl1, wl2, out);
    k1<<<6400, 64, 0, stream>>>(x, wl1, u1);
    kf<<<256, 256, 0, stream>>>(u1, wl2, lw, out);
}